// Round 6
// baseline (1218.319 us; speedup 1.0000x reference)
//
#include <hip/hip_runtime.h>
#include <hip/hip_bf16.h>

#define NN 50000
#define EE 800000
#define FIN 256
#define HIDC 128
#define NGRAPH 50
#define POOL_CHUNKS 32

typedef __attribute__((ext_vector_type(8))) short bf16x8;
typedef __attribute__((ext_vector_type(4))) float f32x4;

__device__ __forceinline__ float lrelu(float x) { return x > 0.f ? x : 0.2f * x; }

__device__ __forceinline__ unsigned short f2bf(float f) {
  union { float f; unsigned u; } c; c.f = f;
  unsigned u = c.u;
  unsigned r = (u + 0x7fffu + ((u >> 16) & 1u)) >> 16;   // RNE
  return (unsigned short)r;
}
__device__ __forceinline__ float bf2f(unsigned short b) {
  union { unsigned u; float f; } c; c.u = ((unsigned)b) << 16;
  return c.f;
}

// ---------------- CSR build ----------------
__global__ void hist_kernel(const int* __restrict__ dst, int* __restrict__ deg) {
  int e = blockIdx.x * blockDim.x + threadIdx.x;
  if (e < EE) atomicAdd(&deg[dst[e]], 1);
}

// single block, 1024 threads: per-thread serial chunk + wave shuffle scan + LDS wave-sum scan.
__global__ __launch_bounds__(1024)
void scan_kernel(const int* __restrict__ deg, int* __restrict__ indptr,
                 int* __restrict__ cursor) {
  __shared__ int wsum[16];
  const int tid = threadIdx.x;
  const int lane = tid & 63, wid = tid >> 6;
  const int PER = (NN + 1023) / 1024;  // 49
  int base = tid * PER;
  int n = NN - base; if (n < 0) n = 0; if (n > PER) n = PER;
  int sum = 0;
  for (int j = 0; j < n; j++) sum += deg[base + j];
  int inc = sum;
#pragma unroll
  for (int off = 1; off < 64; off <<= 1) {
    int t = __shfl_up(inc, off);
    if (lane >= off) inc += t;
  }
  if (lane == 63) wsum[wid] = inc;
  __syncthreads();
  if (tid == 0) {
    int run = 0;
#pragma unroll
    for (int w = 0; w < 16; w++) { int t = wsum[w]; wsum[w] = run; run += t; }
  }
  __syncthreads();
  int excl = wsum[wid] + inc - sum;   // exclusive prefix of this thread's chunk
  int running = excl;
  for (int j = 0; j < n; j++) {
    int d = deg[base + j];
    indptr[base + j] = running;
    cursor[base + j] = running;
    running += d;
  }
  if (tid == 1023) indptr[NN] = excl + sum;  // n==0 here, excl == grand total
}

__global__ void scatter_kernel(const int* __restrict__ src, const int* __restrict__ dst,
                               int* __restrict__ cursor, int* __restrict__ csr_src) {
  int e = blockIdx.x * blockDim.x + threadIdx.x;
  if (e < EE) {
    int d = dst[e];
    int slot = atomicAdd(&cursor[d], 1);
    csr_src[slot] = src[e];
  }
}

// ---------------- weight transpose + bf16 hi/lo split: W[K][N] -> Wt[N][K] ----------------
__global__ __launch_bounds__(256)
void transpose_split(const float* __restrict__ W, unsigned short* __restrict__ WtHi,
                     unsigned short* __restrict__ WtLo, int K, int N) {
  __shared__ float t[32][33];
  int k0 = blockIdx.y * 32, n0 = blockIdx.x * 32;
  int tx = threadIdx.x & 31, ty = threadIdx.x >> 5;   // ty 0..7
  for (int r = ty; r < 32; r += 8) t[r][tx] = W[(size_t)(k0 + r) * N + n0 + tx];
  __syncthreads();
  for (int r = ty; r < 32; r += 8) {
    float v = t[tx][r];
    unsigned short hb = f2bf(v);
    size_t o = (size_t)(n0 + r) * K + k0 + tx;
    WtHi[o] = hb;
    WtLo[o] = f2bf(v - bf2f(hb));
  }
}

// ---------------- x -> hi/lo split (vectorized by 4) ----------------
__global__ void split_x(const float* __restrict__ in, unsigned short* __restrict__ hi,
                        unsigned short* __restrict__ lo, int n4) {
  int i = blockIdx.x * blockDim.x + threadIdx.x;
  if (i >= n4) return;
  float4 v = ((const float4*)in)[i];
  unsigned short h[4], l[4];
  float a[4] = {v.x, v.y, v.z, v.w};
#pragma unroll
  for (int j = 0; j < 4; j++) { h[j] = f2bf(a[j]); l[j] = f2bf(a[j] - bf2f(h[j])); }
  ((ushort4*)hi)[i] = make_ushort4(h[0], h[1], h[2], h[3]);
  ((ushort4*)lo)[i] = make_ushort4(l[0], l[1], l[2], l[3]);
}

// ---------------- split-bf16 MFMA GEMM: C[M,Nc] = (Ahi+Alo) @ (Bt_hi+Bt_lo)^T ----------------
// A: [M][K] bf16 rows; Bt: [Nc][K] bf16 rows (pre-transposed weights). 3-term split product.
// 128x128 tile, BK=32, 4 waves of 64x64. LDS: 4 sub-tiles [128][32] with chunk XOR swizzle.
__global__ __launch_bounds__(256)
void gemm_split(const unsigned short* __restrict__ Ahi, const unsigned short* __restrict__ Alo,
                const unsigned short* __restrict__ Bhi, const unsigned short* __restrict__ Blo,
                float* __restrict__ C, int M, int K, int Ncols) {
  __shared__ unsigned short smem[4 * 128 * 32];
  const int tid = threadIdx.x;
  const int lane = tid & 63;
  const int wid = tid >> 6;
  const int wr = wid >> 1, wc = wid & 1;
  const int brow0 = blockIdx.y * 128, bcol0 = blockIdx.x * 128;

  f32x4 acc[4][4];
#pragma unroll
  for (int i = 0; i < 4; i++)
#pragma unroll
    for (int j = 0; j < 4; j++) acc[i][j] = (f32x4){0.f, 0.f, 0.f, 0.f};

  for (int k0 = 0; k0 < K; k0 += 32) {
#pragma unroll
    for (int t = 0; t < 8; t++) {
      const int tile = t >> 1;                    // compile-time per unrolled iter
      const int s = ((t & 1) << 8) + tid;         // slot within tile, 0..511
      const int row = s >> 2;
      const int cl = (s & 3) ^ ((row >> 1) & 3);  // logical 16B chunk to fetch
      const unsigned short* gsrc;
      if (tile < 2) {
        int grow = brow0 + row; if (grow > M - 1) grow = M - 1;
        const unsigned short* base = (tile == 0) ? Ahi : Alo;
        gsrc = base + (size_t)grow * K + k0 + cl * 8;
      } else {
        int gcol = bcol0 + row;
        const unsigned short* base = (tile == 2) ? Bhi : Blo;
        gsrc = base + (size_t)gcol * K + k0 + cl * 8;
      }
      unsigned short* ldst = &smem[(size_t)(tile * 512 + ((t & 1) << 8) + (tid & ~63)) * 8];
      __builtin_amdgcn_global_load_lds((const __attribute__((address_space(1))) void*)gsrc,
                                       (__attribute__((address_space(3))) void*)ldst, 16, 0, 0);
    }
    __syncthreads();

    bf16x8 ah[4], al[4];
#pragma unroll
    for (int mf = 0; mf < 4; mf++) {
      int R = wr * 64 + mf * 16 + (lane & 15);
      int off = R * 32 + ((((lane >> 4)) ^ ((R >> 1) & 3)) << 3);
      ah[mf] = *(const bf16x8*)&smem[off];
      al[mf] = *(const bf16x8*)&smem[4096 + off];
    }
#pragma unroll
    for (int nf = 0; nf < 4; nf++) {
      int R = wc * 64 + nf * 16 + (lane & 15);
      int off = R * 32 + ((((lane >> 4)) ^ ((R >> 1) & 3)) << 3);
      bf16x8 bh = *(const bf16x8*)&smem[8192 + off];
      bf16x8 bl = *(const bf16x8*)&smem[12288 + off];
#pragma unroll
      for (int mf = 0; mf < 4; mf++) {
        acc[mf][nf] = __builtin_amdgcn_mfma_f32_16x16x32_bf16(ah[mf], bh, acc[mf][nf], 0, 0, 0);
        acc[mf][nf] = __builtin_amdgcn_mfma_f32_16x16x32_bf16(al[mf], bh, acc[mf][nf], 0, 0, 0);
        acc[mf][nf] = __builtin_amdgcn_mfma_f32_16x16x32_bf16(ah[mf], bl, acc[mf][nf], 0, 0, 0);
      }
    }
    __syncthreads();
  }

  // epilogue: C/D layout col = lane&15, row = (lane>>4)*4 + reg (m89)
  const int orow = (lane >> 4) * 4;
  const int ocol = lane & 15;
#pragma unroll
  for (int mf = 0; mf < 4; mf++) {
#pragma unroll
    for (int r = 0; r < 4; r++) {
      int grow = brow0 + wr * 64 + mf * 16 + orow + r;
      if (grow < M) {
#pragma unroll
        for (int nf = 0; nf < 4; nf++) {
          int gcol = bcol0 + wc * 64 + nf * 16 + ocol;
          C[(size_t)grow * Ncols + gcol] = acc[mf][nf][r];
        }
      }
    }
  }
}

// ---------------- alpha_s / alpha_d: one wave per (node, head) ----------------
template <int H>
__global__ __launch_bounds__(256)
void alpha_kernel(const float* __restrict__ h, const float* __restrict__ a_s,
                  const float* __restrict__ a_d, float* __restrict__ as_out,
                  float* __restrict__ ad_out) {
  int gw = (blockIdx.x * blockDim.x + threadIdx.x) >> 6;
  int lane = threadIdx.x & 63;
  if (gw >= NN * H) return;
  int node = gw / H, hh = gw % H;
  const float2 hv = *(const float2*)&h[(size_t)node * (H * HIDC) + hh * HIDC + lane * 2];
  const float2 sv = *(const float2*)&a_s[hh * HIDC + lane * 2];
  const float2 dv = *(const float2*)&a_d[hh * HIDC + lane * 2];
  float ss = hv.x * sv.x + hv.y * sv.y;
  float sd = hv.x * dv.x + hv.y * dv.y;
#pragma unroll
  for (int off = 32; off; off >>= 1) {
    ss += __shfl_xor(ss, off);
    sd += __shfl_xor(sd, off);
  }
  if (lane == 0) {
    as_out[node * H + hh] = ss;
    ad_out[node * H + hh] = sd;
  }
}

// ---------------- per-dst-node softmax + weighted aggregation ----------------
// Block-per-node: 4 waves. Passes 1-2 thread-parallel over edges; pass 3 splits
// edges across waves (4x memory-level parallelism on the gather chain) with an
// LDS partial-sum combine. Numerically identical two-pass softmax.
template <int H, int CH, bool SPLIT, bool ELU>  // CH = H * HIDC
__global__ __launch_bounds__(256)
void aggregate_kernel(const float* __restrict__ h, const float* __restrict__ asb,
                      const float* __restrict__ adb, const int* __restrict__ indptr,
                      const int* __restrict__ csr_src, const float* __restrict__ bias,
                      float* __restrict__ outF, unsigned short* __restrict__ outHi,
                      unsigned short* __restrict__ outLo) {
  constexpr int F = CH / 64;  // floats per lane in pass 3
  __shared__ float sAcc[4][CH];
  __shared__ float sM[4][H], sS[4][H];
  __shared__ float fM[H], fR[H];
  const int node = blockIdx.x;
  const int tid = threadIdx.x;
  const int lane = tid & 63, w = tid >> 6;
  const int beg = indptr[node];
  const int deg = indptr[node + 1] - beg;

  float adv[H];
#pragma unroll
  for (int hh = 0; hh < H; hh++) adv[hh] = adb[node * H + hh];

  // ---- pass 1: max over edges (thread-parallel) ----
  float m[H];
#pragma unroll
  for (int hh = 0; hh < H; hh++) m[hh] = -1e30f;
  for (int i = tid; i < deg; i += 256) {
    int s = csr_src[beg + i];
#pragma unroll
    for (int hh = 0; hh < H; hh++)
      m[hh] = fmaxf(m[hh], lrelu(asb[s * H + hh] + adv[hh]));
  }
#pragma unroll
  for (int off = 32; off; off >>= 1)
#pragma unroll
    for (int hh = 0; hh < H; hh++) m[hh] = fmaxf(m[hh], __shfl_xor(m[hh], off));
  if (lane == 0) {
#pragma unroll
    for (int hh = 0; hh < H; hh++) sM[w][hh] = m[hh];
  }
  __syncthreads();
  if (tid < H) {
    float mm = fmaxf(fmaxf(sM[0][tid], sM[1][tid]), fmaxf(sM[2][tid], sM[3][tid]));
    fM[tid] = mm;
  }
  __syncthreads();
#pragma unroll
  for (int hh = 0; hh < H; hh++) m[hh] = fM[hh];

  // ---- pass 2: sum of exp (thread-parallel) ----
  float ssum[H];
#pragma unroll
  for (int hh = 0; hh < H; hh++) ssum[hh] = 0.f;
  for (int i = tid; i < deg; i += 256) {
    int s = csr_src[beg + i];
#pragma unroll
    for (int hh = 0; hh < H; hh++) {
      float e = lrelu(asb[s * H + hh] + adv[hh]);
      ssum[hh] += expf(e - m[hh]);
    }
  }
#pragma unroll
  for (int off = 32; off; off >>= 1)
#pragma unroll
    for (int hh = 0; hh < H; hh++) ssum[hh] += __shfl_xor(ssum[hh], off);
  if (lane == 0) {
#pragma unroll
    for (int hh = 0; hh < H; hh++) sS[w][hh] = ssum[hh];
  }
  __syncthreads();
  if (tid < H) {
    float ss = sS[0][tid] + sS[1][tid] + sS[2][tid] + sS[3][tid];
    fR[tid] = 1.f / (ss + 1e-16f);
  }
  __syncthreads();

  // ---- pass 3: weighted gather, wave-parallel over edges ----
  const int myh = (lane * F) / HIDC;  // this lane's channels live in one head
  const float myadv = adv[0 ? 0 : 0] * 0.f + adb[node * H + myh];  // direct load (dyn idx)
  const float mym = fM[myh], myrd = fR[myh];
  float acc[F];
#pragma unroll
  for (int f = 0; f < F; f++) acc[f] = 0.f;
  for (int i = w; i < deg; i += 4) {
    int s = csr_src[beg + i];
    float e = lrelu(asb[s * H + myh] + myadv);
    float wgt = expf(e - mym) * myrd;
    const float* hrow = &h[(size_t)s * CH + lane * F];
    if constexpr (F == 8) {
      float4 v0 = *(const float4*)&hrow[0];
      float4 v1 = *(const float4*)&hrow[4];
      acc[0] += wgt * v0.x; acc[1] += wgt * v0.y; acc[2] += wgt * v0.z; acc[3] += wgt * v0.w;
      acc[4] += wgt * v1.x; acc[5] += wgt * v1.y; acc[6] += wgt * v1.z; acc[7] += wgt * v1.w;
    } else {
      float2 v0 = *(const float2*)&hrow[0];
      acc[0] += wgt * v0.x;
      acc[1] += wgt * v0.y;
    }
  }
  // write wave partials
  if constexpr (F == 8) {
    *(float4*)&sAcc[w][lane * 8]     = make_float4(acc[0], acc[1], acc[2], acc[3]);
    *(float4*)&sAcc[w][lane * 8 + 4] = make_float4(acc[4], acc[5], acc[6], acc[7]);
  } else {
    *(float2*)&sAcc[w][lane * 2] = make_float2(acc[0], acc[1]);
  }
  __syncthreads();

  // ---- combine + epilogue: thread per channel (strided) ----
  for (int c = tid; c < CH; c += 256) {
    float v = sAcc[0][c] + sAcc[1][c] + sAcc[2][c] + sAcc[3][c];
    v += bias[c];
    if constexpr (ELU) v = v > 0.f ? v : expm1f(v);
    if constexpr (SPLIT) {
      unsigned short hb = f2bf(v);
      outHi[(size_t)node * CH + c] = hb;
      outLo[(size_t)node * CH + c] = f2bf(v - bf2f(hb));
    } else {
      outF[(size_t)node * CH + c] = v;
    }
  }
}

// ---------------- global mean pool: two-phase deterministic reduction ----------------
__global__ void pool_partial(const float* __restrict__ node_emb, const int* __restrict__ batch,
                             float* __restrict__ part) {
  int g = blockIdx.x, chunk = blockIdx.y, c = threadIdx.x;
  int lo = 0, hi = NN;
  while (lo < hi) { int mid = (lo + hi) >> 1; if (batch[mid] < g) lo = mid + 1; else hi = mid; }
  int s = lo;
  lo = 0; hi = NN;
  while (lo < hi) { int mid = (lo + hi) >> 1; if (batch[mid] < g + 1) lo = mid + 1; else hi = mid; }
  int e = lo;
  int per = (e - s + POOL_CHUNKS - 1) / POOL_CHUNKS;
  int cs = s + chunk * per;
  int ce = cs + per; if (ce > e) ce = e;
  float sum = 0.f;
  for (int i = cs; i < ce; i++) sum += node_emb[(size_t)i * HIDC + c];
  part[((size_t)chunk * NGRAPH + g) * HIDC + c] = sum;
}

__global__ void pool_final(const float* __restrict__ part, const int* __restrict__ batch,
                           float* __restrict__ gout) {
  int g = blockIdx.x, c = threadIdx.x;
  int lo = 0, hi = NN;
  while (lo < hi) { int mid = (lo + hi) >> 1; if (batch[mid] < g) lo = mid + 1; else hi = mid; }
  int s = lo;
  lo = 0; hi = NN;
  while (lo < hi) { int mid = (lo + hi) >> 1; if (batch[mid] < g + 1) lo = mid + 1; else hi = mid; }
  int e = lo;
  float sum = 0.f;
#pragma unroll
  for (int k = 0; k < POOL_CHUNKS; k++) sum += part[((size_t)k * NGRAPH + g) * HIDC + c];
  gout[g * HIDC + c] = sum / fmaxf((float)(e - s), 1.0f);
}

extern "C" void kernel_launch(void* const* d_in, const int* in_sizes, int n_in,
                              void* d_out, int out_size, void* d_ws, size_t ws_size,
                              hipStream_t stream) {
  const float* x   = (const float*)d_in[0];
  const int* ei    = (const int*)d_in[1];
  const int* batch = (const int*)d_in[2];
  const float* W1  = (const float*)d_in[3];
  const float* a1s = (const float*)d_in[4];
  const float* a1d = (const float*)d_in[5];
  const float* b1  = (const float*)d_in[6];
  const float* W2  = (const float*)d_in[7];
  const float* a2s = (const float*)d_in[8];
  const float* a2d = (const float*)d_in[9];
  const float* b2  = (const float*)d_in[10];
  const float* W3  = (const float*)d_in[11];
  const float* a3s = (const float*)d_in[12];
  const float* a3d = (const float*)d_in[13];
  const float* b3  = (const float*)d_in[14];
  float* out_node  = (float*)d_out;
  float* out_graph = out_node + (size_t)NN * HIDC;

  char* p = (char*)d_ws;
  auto take = [&](size_t bytes) {
    char* cur = p;
    p += (bytes + 255) & ~(size_t)255;
    return cur;
  };
  unsigned short* hHi = (unsigned short*)take((size_t)NN * 512 * 2);
  unsigned short* hLo = (unsigned short*)take((size_t)NN * 512 * 2);
  float* bufF = (float*)take((size_t)NN * 512 * 4);
  float* asb  = (float*)take((size_t)NN * 4 * 4);
  float* adb  = (float*)take((size_t)NN * 4 * 4);
  unsigned short* W1tH = (unsigned short*)take((size_t)512 * 256 * 2);
  unsigned short* W1tL = (unsigned short*)take((size_t)512 * 256 * 2);
  unsigned short* W2tH = (unsigned short*)take((size_t)512 * 512 * 2);
  unsigned short* W2tL = (unsigned short*)take((size_t)512 * 512 * 2);
  unsigned short* W3tH = (unsigned short*)take((size_t)128 * 512 * 2);
  unsigned short* W3tL = (unsigned short*)take((size_t)128 * 512 * 2);
  int* deg    = (int*)take((size_t)NN * 4);
  int* indptr = (int*)take((size_t)(NN + 1) * 4);
  int* cursor = (int*)take((size_t)NN * 4);
  int* csr    = (int*)take((size_t)EE * 4);
  float* poolws = (float*)take((size_t)POOL_CHUNKS * NGRAPH * HIDC * 4);

  const int* srcv = ei;
  const int* dstv = ei + EE;

  // CSR build
  hipMemsetAsync(deg, 0, (size_t)NN * 4, stream);
  hist_kernel<<<(EE + 255) / 256, 256, 0, stream>>>(dstv, deg);
  scan_kernel<<<1, 1024, 0, stream>>>(deg, indptr, cursor);
  scatter_kernel<<<(EE + 255) / 256, 256, 0, stream>>>(srcv, dstv, cursor, csr);

  // weight transpose + split; x split (x_hi/x_lo alias hHi/hLo — dead before aggregate1 writes)
  transpose_split<<<dim3(512 / 32, 256 / 32), 256, 0, stream>>>(W1, W1tH, W1tL, 256, 512);
  transpose_split<<<dim3(512 / 32, 512 / 32), 256, 0, stream>>>(W2, W2tH, W2tL, 512, 512);
  transpose_split<<<dim3(128 / 32, 512 / 32), 256, 0, stream>>>(W3, W3tH, W3tL, 512, 128);
  split_x<<<(NN * FIN / 4 + 255) / 256, 256, 0, stream>>>(x, hHi, hLo, NN * FIN / 4);

  dim3 blk(256);
  const int rowBlocks = (NN + 127) / 128;
  // layer 1
  gemm_split<<<dim3(4, rowBlocks), blk, 0, stream>>>(hHi, hLo, W1tH, W1tL, bufF, NN, 256, 512);
  alpha_kernel<4><<<(NN * 4 + 3) / 4, blk, 0, stream>>>(bufF, a1s, a1d, asb, adb);
  aggregate_kernel<4, 512, true, true><<<NN, blk, 0, stream>>>(
      bufF, asb, adb, indptr, csr, b1, nullptr, hHi, hLo);
  // layer 2
  gemm_split<<<dim3(4, rowBlocks), blk, 0, stream>>>(hHi, hLo, W2tH, W2tL, bufF, NN, 512, 512);
  alpha_kernel<4><<<(NN * 4 + 3) / 4, blk, 0, stream>>>(bufF, a2s, a2d, asb, adb);
  aggregate_kernel<4, 512, true, true><<<NN, blk, 0, stream>>>(
      bufF, asb, adb, indptr, csr, b2, nullptr, hHi, hLo);
  // layer 3
  gemm_split<<<dim3(1, rowBlocks), blk, 0, stream>>>(hHi, hLo, W3tH, W3tL, bufF, NN, 512, 128);
  alpha_kernel<1><<<(NN + 3) / 4, blk, 0, stream>>>(bufF, a3s, a3d, asb, adb);
  aggregate_kernel<1, 128, false, false><<<NN, blk, 0, stream>>>(
      bufF, asb, adb, indptr, csr, b3, out_node, nullptr, nullptr);
  // per-graph mean pool (two-phase, deterministic)
  pool_partial<<<dim3(NGRAPH, POOL_CHUNKS), HIDC, 0, stream>>>(out_node, batch, poolws);
  pool_final<<<NGRAPH, HIDC, 0, stream>>>(poolws, batch, out_graph);
}

// Round 9
// 1133.900 us; speedup vs baseline: 1.0744x; 1.0744x over previous
//
#include <hip/hip_runtime.h>
#include <hip/hip_bf16.h>

#define NN 50000
#define EE 800000
#define FIN 256
#define HIDC 128
#define NGRAPH 50
#define POOL_CHUNKS 32

typedef __attribute__((ext_vector_type(8))) short bf16x8;
typedef __attribute__((ext_vector_type(4))) float f32x4;
typedef __attribute__((ext_vector_type(8))) _Float16 f16x8;
typedef __attribute__((ext_vector_type(2))) _Float16 f16x2;

__device__ __forceinline__ float lrelu(float x) { return x > 0.f ? x : 0.2f * x; }

__device__ __forceinline__ unsigned short f2bf(float f) {
  union { float f; unsigned u; } c; c.f = f;
  unsigned u = c.u;
  unsigned r = (u + 0x7fffu + ((u >> 16) & 1u)) >> 16;   // RNE
  return (unsigned short)r;
}
__device__ __forceinline__ float bf2f(unsigned short b) {
  union { unsigned u; float f; } c; c.u = ((unsigned)b) << 16;
  return c.f;
}

// ---------------- CSR build ----------------
__global__ void hist_kernel(const int* __restrict__ dst, int* __restrict__ deg) {
  int e = blockIdx.x * blockDim.x + threadIdx.x;
  if (e < EE) atomicAdd(&deg[dst[e]], 1);
}

// single block, 1024 threads: per-thread serial chunk + wave shuffle scan + LDS wave-sum scan.
__global__ __launch_bounds__(1024)
void scan_kernel(const int* __restrict__ deg, int* __restrict__ indptr,
                 int* __restrict__ cursor) {
  __shared__ int wsum[16];
  const int tid = threadIdx.x;
  const int lane = tid & 63, wid = tid >> 6;
  const int PER = (NN + 1023) / 1024;  // 49
  int base = tid * PER;
  int n = NN - base; if (n < 0) n = 0; if (n > PER) n = PER;
  int sum = 0;
  for (int j = 0; j < n; j++) sum += deg[base + j];
  int inc = sum;
#pragma unroll
  for (int off = 1; off < 64; off <<= 1) {
    int t = __shfl_up(inc, off);
    if (lane >= off) inc += t;
  }
  if (lane == 63) wsum[wid] = inc;
  __syncthreads();
  if (tid == 0) {
    int run = 0;
#pragma unroll
    for (int w = 0; w < 16; w++) { int t = wsum[w]; wsum[w] = run; run += t; }
  }
  __syncthreads();
  int excl = wsum[wid] + inc - sum;   // exclusive prefix of this thread's chunk
  int running = excl;
  for (int j = 0; j < n; j++) {
    int d = deg[base + j];
    indptr[base + j] = running;
    cursor[base + j] = running;
    running += d;
  }
  if (tid == 1023) indptr[NN] = excl + sum;  // n==0 here, excl == grand total
}

__global__ void scatter_kernel(const int* __restrict__ src, const int* __restrict__ dst,
                               int* __restrict__ cursor, int* __restrict__ csr_src) {
  int e = blockIdx.x * blockDim.x + threadIdx.x;
  if (e < EE) {
    int d = dst[e];
    int slot = atomicAdd(&cursor[d], 1);
    csr_src[slot] = src[e];
  }
}

// ---------------- weight transpose + bf16 hi/lo split: W[K][N] -> Wt[N][K] ----------------
__global__ __launch_bounds__(256)
void transpose_split(const float* __restrict__ W, unsigned short* __restrict__ WtHi,
                     unsigned short* __restrict__ WtLo, int K, int N) {
  __shared__ float t[32][33];
  int k0 = blockIdx.y * 32, n0 = blockIdx.x * 32;
  int tx = threadIdx.x & 31, ty = threadIdx.x >> 5;   // ty 0..7
  for (int r = ty; r < 32; r += 8) t[r][tx] = W[(size_t)(k0 + r) * N + n0 + tx];
  __syncthreads();
  for (int r = ty; r < 32; r += 8) {
    float v = t[tx][r];
    unsigned short hb = f2bf(v);
    size_t o = (size_t)(n0 + r) * K + k0 + tx;
    WtHi[o] = hb;
    WtLo[o] = f2bf(v - bf2f(hb));
  }
}

// ---------------- x -> hi/lo split (vectorized by 4) ----------------
__global__ void split_x(const float* __restrict__ in, unsigned short* __restrict__ hi,
                        unsigned short* __restrict__ lo, int n4) {
  int i = blockIdx.x * blockDim.x + threadIdx.x;
  if (i >= n4) return;
  float4 v = ((const float4*)in)[i];
  unsigned short h[4], l[4];
  float a[4] = {v.x, v.y, v.z, v.w};
#pragma unroll
  for (int j = 0; j < 4; j++) { h[j] = f2bf(a[j]); l[j] = f2bf(a[j] - bf2f(h[j])); }
  ((ushort4*)hi)[i] = make_ushort4(h[0], h[1], h[2], h[3]);
  ((ushort4*)lo)[i] = make_ushort4(l[0], l[1], l[2], l[3]);
}

// ---------------- split-bf16 MFMA GEMM: C[M,Nc] = (Ahi+Alo) @ (Bt_hi+Bt_lo)^T ----------------
// OUT16: write fp16 h (value path for layers 1-2); else f32.
template <bool OUT16>
__global__ __launch_bounds__(256)
void gemm_split(const unsigned short* __restrict__ Ahi, const unsigned short* __restrict__ Alo,
                const unsigned short* __restrict__ Bhi, const unsigned short* __restrict__ Blo,
                float* __restrict__ C, _Float16* __restrict__ Ch, int M, int K, int Ncols) {
  __shared__ unsigned short smem[4 * 128 * 32];
  const int tid = threadIdx.x;
  const int lane = tid & 63;
  const int wid = tid >> 6;
  const int wr = wid >> 1, wc = wid & 1;
  const int brow0 = blockIdx.y * 128, bcol0 = blockIdx.x * 128;

  f32x4 acc[4][4];
#pragma unroll
  for (int i = 0; i < 4; i++)
#pragma unroll
    for (int j = 0; j < 4; j++) acc[i][j] = (f32x4){0.f, 0.f, 0.f, 0.f};

  for (int k0 = 0; k0 < K; k0 += 32) {
#pragma unroll
    for (int t = 0; t < 8; t++) {
      const int tile = t >> 1;                    // compile-time per unrolled iter
      const int s = ((t & 1) << 8) + tid;         // slot within tile, 0..511
      const int row = s >> 2;
      const int cl = (s & 3) ^ ((row >> 1) & 3);  // logical 16B chunk to fetch
      const unsigned short* gsrc;
      if (tile < 2) {
        int grow = brow0 + row; if (grow > M - 1) grow = M - 1;
        const unsigned short* base = (tile == 0) ? Ahi : Alo;
        gsrc = base + (size_t)grow * K + k0 + cl * 8;
      } else {
        int gcol = bcol0 + row;
        const unsigned short* base = (tile == 2) ? Bhi : Blo;
        gsrc = base + (size_t)gcol * K + k0 + cl * 8;
      }
      unsigned short* ldst = &smem[(size_t)(tile * 512 + ((t & 1) << 8) + (tid & ~63)) * 8];
      __builtin_amdgcn_global_load_lds((const __attribute__((address_space(1))) void*)gsrc,
                                       (__attribute__((address_space(3))) void*)ldst, 16, 0, 0);
    }
    __syncthreads();

    bf16x8 ah[4], al[4];
#pragma unroll
    for (int mf = 0; mf < 4; mf++) {
      int R = wr * 64 + mf * 16 + (lane & 15);
      int off = R * 32 + ((((lane >> 4)) ^ ((R >> 1) & 3)) << 3);
      ah[mf] = *(const bf16x8*)&smem[off];
      al[mf] = *(const bf16x8*)&smem[4096 + off];
    }
#pragma unroll
    for (int nf = 0; nf < 4; nf++) {
      int R = wc * 64 + nf * 16 + (lane & 15);
      int off = R * 32 + ((((lane >> 4)) ^ ((R >> 1) & 3)) << 3);
      bf16x8 bh = *(const bf16x8*)&smem[8192 + off];
      bf16x8 bl = *(const bf16x8*)&smem[12288 + off];
#pragma unroll
      for (int mf = 0; mf < 4; mf++) {
        acc[mf][nf] = __builtin_amdgcn_mfma_f32_16x16x32_bf16(ah[mf], bh, acc[mf][nf], 0, 0, 0);
        acc[mf][nf] = __builtin_amdgcn_mfma_f32_16x16x32_bf16(al[mf], bh, acc[mf][nf], 0, 0, 0);
        acc[mf][nf] = __builtin_amdgcn_mfma_f32_16x16x32_bf16(ah[mf], bl, acc[mf][nf], 0, 0, 0);
      }
    }
    __syncthreads();
  }

  // epilogue: C/D layout col = lane&15, row = (lane>>4)*4 + reg (m89)
  const int orow = (lane >> 4) * 4;
  const int ocol = lane & 15;
#pragma unroll
  for (int mf = 0; mf < 4; mf++) {
#pragma unroll
    for (int r = 0; r < 4; r++) {
      int grow = brow0 + wr * 64 + mf * 16 + orow + r;
      if (grow < M) {
#pragma unroll
        for (int nf = 0; nf < 4; nf++) {
          int gcol = bcol0 + wc * 64 + nf * 16 + ocol;
          if constexpr (OUT16) Ch[(size_t)grow * Ncols + gcol] = (_Float16)acc[mf][nf][r];
          else                 C[(size_t)grow * Ncols + gcol] = acc[mf][nf][r];
        }
      }
    }
  }
}

// ---------------- alpha_s / alpha_d: one wave per (node, head) ----------------
template <int H, bool IN16>
__global__ __launch_bounds__(256)
void alpha_kernel(const float* __restrict__ hF, const _Float16* __restrict__ h16,
                  const float* __restrict__ a_s, const float* __restrict__ a_d,
                  float* __restrict__ as_out, float* __restrict__ ad_out) {
  int gw = (blockIdx.x * blockDim.x + threadIdx.x) >> 6;
  int lane = threadIdx.x & 63;
  if (gw >= NN * H) return;
  int node = gw / H, hh = gw % H;
  float hx, hy;
  if constexpr (IN16) {
    f16x2 hv = *(const f16x2*)&h16[(size_t)node * (H * HIDC) + hh * HIDC + lane * 2];
    hx = (float)hv[0]; hy = (float)hv[1];
  } else {
    float2 hv = *(const float2*)&hF[(size_t)node * (H * HIDC) + hh * HIDC + lane * 2];
    hx = hv.x; hy = hv.y;
  }
  const float2 sv = *(const float2*)&a_s[hh * HIDC + lane * 2];
  const float2 dv = *(const float2*)&a_d[hh * HIDC + lane * 2];
  float ss = hx * sv.x + hy * sv.y;
  float sd = hx * dv.x + hy * dv.y;
#pragma unroll
  for (int off = 32; off; off >>= 1) {
    ss += __shfl_xor(ss, off);
    sd += __shfl_xor(sd, off);
  }
  if (lane == 0) {
    as_out[node * H + hh] = ss;
    ad_out[node * H + hh] = sd;
  }
}

// ---------------- per-dst-node softmax + weighted aggregation ----------------
// Block-per-node: 4 waves. Passes 1-2 thread-parallel; pass 3 wave-split gather
// (fp16 values for IN16) + LDS combine. Two-pass softmax, exact weights from f32 asb/adb.
template <int H, int CH, bool IN16, bool SPLIT, bool ELU>
__global__ __launch_bounds__(256)
void aggregate_kernel(const float* __restrict__ hF, const _Float16* __restrict__ h16,
                      const float* __restrict__ asb, const float* __restrict__ adb,
                      const int* __restrict__ indptr, const int* __restrict__ csr_src,
                      const float* __restrict__ bias, float* __restrict__ outF,
                      unsigned short* __restrict__ outHi, unsigned short* __restrict__ outLo) {
  constexpr int F = CH / 64;  // channels per lane in pass 3
  __shared__ float sAcc[4][CH];
  __shared__ float sM[4][H], sS[4][H];
  __shared__ float fM[H], fR[H];
  const int node = blockIdx.x;
  const int tid = threadIdx.x;
  const int lane = tid & 63, w = tid >> 6;
  const int beg = indptr[node];
  const int deg = indptr[node + 1] - beg;

  float adv[H];
#pragma unroll
  for (int hh = 0; hh < H; hh++) adv[hh] = adb[node * H + hh];

  // ---- pass 1: max over edges ----
  float m[H];
#pragma unroll
  for (int hh = 0; hh < H; hh++) m[hh] = -1e30f;
  for (int i = tid; i < deg; i += 256) {
    int s = csr_src[beg + i];
#pragma unroll
    for (int hh = 0; hh < H; hh++)
      m[hh] = fmaxf(m[hh], lrelu(asb[s * H + hh] + adv[hh]));
  }
#pragma unroll
  for (int off = 32; off; off >>= 1)
#pragma unroll
    for (int hh = 0; hh < H; hh++) m[hh] = fmaxf(m[hh], __shfl_xor(m[hh], off));
  if (lane == 0) {
#pragma unroll
    for (int hh = 0; hh < H; hh++) sM[w][hh] = m[hh];
  }
  __syncthreads();
  if (tid < H) {
    fM[tid] = fmaxf(fmaxf(sM[0][tid], sM[1][tid]), fmaxf(sM[2][tid], sM[3][tid]));
  }
  __syncthreads();
#pragma unroll
  for (int hh = 0; hh < H; hh++) m[hh] = fM[hh];

  // ---- pass 2: sum of exp ----
  float ssum[H];
#pragma unroll
  for (int hh = 0; hh < H; hh++) ssum[hh] = 0.f;
  for (int i = tid; i < deg; i += 256) {
    int s = csr_src[beg + i];
#pragma unroll
    for (int hh = 0; hh < H; hh++) {
      float e = lrelu(asb[s * H + hh] + adv[hh]);
      ssum[hh] += expf(e - m[hh]);
    }
  }
#pragma unroll
  for (int off = 32; off; off >>= 1)
#pragma unroll
    for (int hh = 0; hh < H; hh++) ssum[hh] += __shfl_xor(ssum[hh], off);
  if (lane == 0) {
#pragma unroll
    for (int hh = 0; hh < H; hh++) sS[w][hh] = ssum[hh];
  }
  __syncthreads();
  if (tid < H) {
    float ss = sS[0][tid] + sS[1][tid] + sS[2][tid] + sS[3][tid];
    fR[tid] = 1.f / (ss + 1e-16f);
  }
  __syncthreads();

  // ---- pass 3: weighted gather, wave-parallel over edges ----
  const int myh = (lane * F) / HIDC;
  const float myadv = adb[node * H + myh];
  const float mym = fM[myh], myrd = fR[myh];
  float acc[F];
#pragma unroll
  for (int f = 0; f < F; f++) acc[f] = 0.f;
  for (int i = w; i < deg; i += 4) {
    int s = csr_src[beg + i];
    float e = lrelu(asb[s * H + myh] + myadv);
    float wgt = expf(e - mym) * myrd;
    if constexpr (IN16) {
      if constexpr (F == 8) {
        f16x8 v = *(const f16x8*)&h16[(size_t)s * CH + lane * 8];
#pragma unroll
        for (int f = 0; f < 8; f++) acc[f] += wgt * (float)v[f];
      } else {
        f16x2 v = *(const f16x2*)&h16[(size_t)s * CH + lane * 2];
        acc[0] += wgt * (float)v[0];
        acc[1] += wgt * (float)v[1];
      }
    } else {
      const float* hrow = &hF[(size_t)s * CH + lane * F];
      if constexpr (F == 8) {
        float4 v0 = *(const float4*)&hrow[0];
        float4 v1 = *(const float4*)&hrow[4];
        acc[0] += wgt * v0.x; acc[1] += wgt * v0.y; acc[2] += wgt * v0.z; acc[3] += wgt * v0.w;
        acc[4] += wgt * v1.x; acc[5] += wgt * v1.y; acc[6] += wgt * v1.z; acc[7] += wgt * v1.w;
      } else {
        float2 v0 = *(const float2*)&hrow[0];
        acc[0] += wgt * v0.x;
        acc[1] += wgt * v0.y;
      }
    }
  }
  // write wave partials
  if constexpr (F == 8) {
    *(float4*)&sAcc[w][lane * 8]     = make_float4(acc[0], acc[1], acc[2], acc[3]);
    *(float4*)&sAcc[w][lane * 8 + 4] = make_float4(acc[4], acc[5], acc[6], acc[7]);
  } else {
    *(float2*)&sAcc[w][lane * 2] = make_float2(acc[0], acc[1]);
  }
  __syncthreads();

  // ---- combine + epilogue ----
  for (int c = tid; c < CH; c += 256) {
    float v = sAcc[0][c] + sAcc[1][c] + sAcc[2][c] + sAcc[3][c];
    v += bias[c];
    if constexpr (ELU) v = v > 0.f ? v : expm1f(v);
    if constexpr (SPLIT) {
      unsigned short hb = f2bf(v);
      outHi[(size_t)node * CH + c] = hb;
      outLo[(size_t)node * CH + c] = f2bf(v - bf2f(hb));
    } else {
      outF[(size_t)node * CH + c] = v;
    }
  }
}

// ---------------- global mean pool: two-phase deterministic reduction ----------------
__global__ void pool_partial(const float* __restrict__ node_emb, const int* __restrict__ batch,
                             float* __restrict__ part) {
  int g = blockIdx.x, chunk = blockIdx.y, c = threadIdx.x;
  int lo = 0, hi = NN;
  while (lo < hi) { int mid = (lo + hi) >> 1; if (batch[mid] < g) lo = mid + 1; else hi = mid; }
  int s = lo;
  lo = 0; hi = NN;
  while (lo < hi) { int mid = (lo + hi) >> 1; if (batch[mid] < g + 1) lo = mid + 1; else hi = mid; }
  int e = lo;
  int per = (e - s + POOL_CHUNKS - 1) / POOL_CHUNKS;
  int cs = s + chunk * per;
  int ce = cs + per; if (ce > e) ce = e;
  float sum = 0.f;
  for (int i = cs; i < ce; i++) sum += node_emb[(size_t)i * HIDC + c];
  part[((size_t)chunk * NGRAPH + g) * HIDC + c] = sum;
}

__global__ void pool_final(const float* __restrict__ part, const int* __restrict__ batch,
                           float* __restrict__ gout) {
  int g = blockIdx.x, c = threadIdx.x;
  int lo = 0, hi = NN;
  while (lo < hi) { int mid = (lo + hi) >> 1; if (batch[mid] < g) lo = mid + 1; else hi = mid; }
  int s = lo;
  lo = 0; hi = NN;
  while (lo < hi) { int mid = (lo + hi) >> 1; if (batch[mid] < g + 1) lo = mid + 1; else hi = mid; }
  int e = lo;
  float sum = 0.f;
#pragma unroll
  for (int k = 0; k < POOL_CHUNKS; k++) sum += part[((size_t)k * NGRAPH + g) * HIDC + c];
  gout[g * HIDC + c] = sum / fmaxf((float)(e - s), 1.0f);
}

extern "C" void kernel_launch(void* const* d_in, const int* in_sizes, int n_in,
                              void* d_out, int out_size, void* d_ws, size_t ws_size,
                              hipStream_t stream) {
  const float* x   = (const float*)d_in[0];
  const int* ei    = (const int*)d_in[1];
  const int* batch = (const int*)d_in[2];
  const float* W1  = (const float*)d_in[3];
  const float* a1s = (const float*)d_in[4];
  const float* a1d = (const float*)d_in[5];
  const float* b1  = (const float*)d_in[6];
  const float* W2  = (const float*)d_in[7];
  const float* a2s = (const float*)d_in[8];
  const float* a2d = (const float*)d_in[9];
  const float* b2  = (const float*)d_in[10];
  const float* W3  = (const float*)d_in[11];
  const float* a3s = (const float*)d_in[12];
  const float* a3d = (const float*)d_in[13];
  const float* b3  = (const float*)d_in[14];
  float* out_node  = (float*)d_out;
  float* out_graph = out_node + (size_t)NN * HIDC;

  char* p = (char*)d_ws;
  auto take = [&](size_t bytes) {
    char* cur = p;
    p += (bytes + 255) & ~(size_t)255;
    return cur;
  };
  unsigned short* hHi = (unsigned short*)take((size_t)NN * 512 * 2);
  unsigned short* hLo = (unsigned short*)take((size_t)NN * 512 * 2);
  _Float16* h16 = (_Float16*)take((size_t)NN * 512 * 2);
  float* bufF = (float*)take((size_t)NN * HIDC * 4);   // layer-3 f32 h only
  float* asb  = (float*)take((size_t)NN * 4 * 4);
  float* adb  = (float*)take((size_t)NN * 4 * 4);
  unsigned short* W1tH = (unsigned short*)take((size_t)512 * 256 * 2);
  unsigned short* W1tL = (unsigned short*)take((size_t)512 * 256 * 2);
  unsigned short* W2tH = (unsigned short*)take((size_t)512 * 512 * 2);
  unsigned short* W2tL = (unsigned short*)take((size_t)512 * 512 * 2);
  unsigned short* W3tH = (unsigned short*)take((size_t)128 * 512 * 2);
  unsigned short* W3tL = (unsigned short*)take((size_t)128 * 512 * 2);
  int* deg    = (int*)take((size_t)NN * 4);
  int* indptr = (int*)take((size_t)(NN + 1) * 4);
  int* cursor = (int*)take((size_t)NN * 4);
  int* csr    = (int*)take((size_t)EE * 4);
  float* poolws = (float*)take((size_t)POOL_CHUNKS * NGRAPH * HIDC * 4);

  const int* srcv = ei;
  const int* dstv = ei + EE;

  // CSR build
  hipMemsetAsync(deg, 0, (size_t)NN * 4, stream);
  hist_kernel<<<(EE + 255) / 256, 256, 0, stream>>>(dstv, deg);
  scan_kernel<<<1, 1024, 0, stream>>>(deg, indptr, cursor);
  scatter_kernel<<<(EE + 255) / 256, 256, 0, stream>>>(srcv, dstv, cursor, csr);

  // weight transpose + split; x split (x_hi/x_lo alias hHi/hLo — dead before aggregate1 writes)
  transpose_split<<<dim3(512 / 32, 256 / 32), 256, 0, stream>>>(W1, W1tH, W1tL, 256, 512);
  transpose_split<<<dim3(512 / 32, 512 / 32), 256, 0, stream>>>(W2, W2tH, W2tL, 512, 512);
  transpose_split<<<dim3(128 / 32, 512 / 32), 256, 0, stream>>>(W3, W3tH, W3tL, 512, 128);
  split_x<<<(NN * FIN / 4 + 255) / 256, 256, 0, stream>>>(x, hHi, hLo, NN * FIN / 4);

  dim3 blk(256);
  const int rowBlocks = (NN + 127) / 128;
  // layer 1 (h in fp16)
  gemm_split<true><<<dim3(4, rowBlocks), blk, 0, stream>>>(hHi, hLo, W1tH, W1tL, nullptr, h16, NN, 256, 512);
  alpha_kernel<4, true><<<(NN * 4 + 3) / 4, blk, 0, stream>>>(nullptr, h16, a1s, a1d, asb, adb);
  aggregate_kernel<4, 512, true, true, true><<<NN, blk, 0, stream>>>(
      nullptr, h16, asb, adb, indptr, csr, b1, nullptr, hHi, hLo);
  // layer 2 (h in fp16)
  gemm_split<true><<<dim3(4, rowBlocks), blk, 0, stream>>>(hHi, hLo, W2tH, W2tL, nullptr, h16, NN, 512, 512);
  alpha_kernel<4, true><<<(NN * 4 + 3) / 4, blk, 0, stream>>>(nullptr, h16, a2s, a2d, asb, adb);
  aggregate_kernel<4, 512, true, true, true><<<NN, blk, 0, stream>>>(
      nullptr, h16, asb, adb, indptr, csr, b2, nullptr, hHi, hLo);
  // layer 3 (full f32 value path to protect final output)
  gemm_split<false><<<dim3(1, rowBlocks), blk, 0, stream>>>(hHi, hLo, W3tH, W3tL, bufF, nullptr, NN, 512, 128);
  alpha_kernel<1, false><<<(NN + 3) / 4, blk, 0, stream>>>(bufF, nullptr, a3s, a3d, asb, adb);
  aggregate_kernel<1, 128, false, false, false><<<NN, blk, 0, stream>>>(
      bufF, nullptr, asb, adb, indptr, csr, b3, out_node, nullptr, nullptr);
  // per-graph mean pool (two-phase, deterministic)
  pool_partial<<<dim3(NGRAPH, POOL_CHUNKS), HIDC, 0, stream>>>(out_node, batch, poolws);
  pool_final<<<NGRAPH, HIDC, 0, stream>>>(poolws, batch, out_graph);
}